// Round 4
// baseline (1040.365 us; speedup 1.0000x reference)
//
#include <hip/hip_runtime.h>
#include <math.h>

#define HOP 441
#define NMEL 80

__device__ __forceinline__ float2 cmulf(float2 a, float2 b) {
    return make_float2(a.x * b.x - a.y * b.y, a.x * b.y + a.y * b.x);
}
__device__ __forceinline__ float2 cadd(float2 a, float2 b) {
    return make_float2(a.x + b.x, a.y + b.y);
}
__device__ __forceinline__ float2 csub(float2 a, float2 b) {
    return make_float2(a.x - b.x, a.y - b.y);
}
__device__ __forceinline__ float2 shx2(float2 v, int m) {
    return make_float2(__shfl_xor(v.x, m, 64), __shfl_xor(v.y, m, 64));
}
__device__ __forceinline__ float2 shidx2(float2 v, int src) {
    return make_float2(__shfl(v.x, src, 64), __shfl(v.y, src, 64));
}
__device__ __forceinline__ int brev6f(int v) {
    return ((v & 1) << 5) | ((v & 2) << 3) | ((v & 4) << 1) |
           ((v & 8) >> 1) | ((v & 16) >> 3) | ((v & 32) >> 5);
}
__device__ __forceinline__ int brevn(int v, int bits) {
    int r = 0;
    for (int i = 0; i < bits; ++i) r |= ((v >> i) & 1) << (bits - 1 - i);
    return r;
}
// w32(m) = exp(-2*pi*i*m/32), m in [0,16) — literal constants (fold at compile time)
__device__ __forceinline__ float2 w32t(int m) {
    constexpr float C[16] = {1.0f, 0.980785280f, 0.923879533f, 0.831469612f,
                             0.707106781f, 0.555570233f, 0.382683432f, 0.195090322f,
                             0.0f, -0.195090322f, -0.382683432f, -0.555570233f,
                             -0.707106781f, -0.831469612f, -0.923879533f, -0.980785280f};
    constexpr float S[16] = {0.0f, 0.195090322f, 0.382683432f, 0.555570233f,
                             0.707106781f, 0.831469612f, 0.923879533f, 0.980785280f,
                             1.0f, 0.980785280f, 0.923879533f, 0.831469612f,
                             0.707106781f, 0.555570233f, 0.382683432f, 0.195090322f};
    return make_float2(C[m], -S[m]);
}
__device__ __forceinline__ unsigned short bf16t(float v) {
    return (unsigned short)(__float_as_uint(v) >> 16);
}

// One wave = one frame. N = FLEN/2 complex FFT as 64 lanes x R regs:
//  1) lane-local R-point DIT FFT (registers, literal twiddles)
//  2) per-lane twiddle w_N^(l*r) (iterated from per-lane base)
//  3) cross-lane 64-point DIF FFT via 6 shfl_xor stages (lanes relabeled l=brev6(p))
//  4) rfft unpack: mirror via shfl_xor(..., 63); bf16 power -> swizzled LDS rows
// 8 waves/block = 8 frames; then one barrier, shared mel matmul, log, store.
template<int FLEN, int SZI>
__global__ __launch_bounds__(512)
void spect_kernel(const float* __restrict__ x, const float* __restrict__ win,
                  const float* __restrict__ mel, float* __restrict__ out,
                  int T, int n0) {
    constexpr int N    = FLEN / 2;                  // complex FFT size
    constexpr int R    = N / 64;                    // regs (complex) per lane
    constexpr int LOGR = (R == 32) ? 5 : ((R == 16) ? 4 : 3);
    constexpr int K    = N + 1;                     // rfft bins
    constexpr int KP   = N + 8;                     // padded row count
    constexpr int HALF = FLEN / 2;
    constexpr int NT   = 512;
    constexpr int FPB  = 8;                         // frames per block (= waves)
    constexpr float PI = 3.14159265358979f;

    __shared__ uint4 pows4[KP];                     // bf16 power, row-swizzled [k][frame8]
    __shared__ float res[FPB * NMEL];
    unsigned short* pows = (unsigned short*)pows4;

    const int tid = threadIdx.x;
    const int sub = tid >> 6;                       // wave = frame
    const int p   = tid & 63;                       // lane
    const int l   = brev6f(p);                      // cross-FFT index held by this lane
    const int b   = blockIdx.y;
    const int t0  = blockIdx.x * FPB;

    for (int i = tid; i < FPB * NMEL; i += NT) res[i] = 0.0f;

    // per-lane constants (frame-invariant)
    float2 W32s, W16s, W8s, W4s, W2s, wl, Pp, ub;
    {
        float s, c;
        sincosf(-PI * (float)(l & 31) / 32.0f, &s, &c); W32s = make_float2(c, s);
        sincosf(-PI * (float)(l & 15) / 16.0f, &s, &c); W16s = make_float2(c, s);
        sincosf(-PI * (float)(l & 7)  /  8.0f, &s, &c); W8s  = make_float2(c, s);
        sincosf(-PI * (float)(l & 3)  /  4.0f, &s, &c); W4s  = make_float2(c, s);
        sincosf(-PI * (float)(l & 1)  /  2.0f, &s, &c); W2s  = make_float2(c, s);
        sincosf(-2.0f * PI * (float)l / (float)N, &s, &c); wl = make_float2(c, s);
        sincosf( PI * (float)p / 64.0f, &s, &c);        Pp = make_float2(c, s);
        sincosf( PI / (float)N, &s, &c);                ub = make_float2(c, s);
    }
    const int mpart = (64 - p) & 63;                // r=0 mirror partner lane

    const float* xb = x + (size_t)b * (size_t)T;
    const int Tp = T + HALF;

    const int t = t0 + sub;
    const bool valid = (t < n0);
    const int start = HOP * t;
    int pad = start + FLEN - Tp; if (pad < 0) pad = 0;
    const int base = start - pad - HALF;

    float2 z[R];
    // load bit-reversed q order: reg j holds sample q = brevn(j); z = x[2i]+i*x[2i+1]
    #pragma unroll
    for (int j = 0; j < R; ++j) {
        const int q  = brevn(j, LOGR);
        const int i  = 64 * q + l;
        const int j0 = 2 * i;
        const float2 wv = ((const float2*)win)[i];
        const int xi0 = base + j0;
        float v0 = (valid && j0 >= pad     && xi0 >= 0)     ? xb[xi0] * wv.x     : 0.0f;
        float v1 = (valid && j0 + 1 >= pad && xi0 + 1 >= 0) ? xb[xi0 + 1] * wv.y : 0.0f;
        z[j] = make_float2(v0, v1);
    }

    // 1) lane-local R-point DIT FFT (output natural order r = reg index)
    #pragma unroll
    for (int h = 1; h < R; h <<= 1) {
        #pragma unroll
        for (int base2 = 0; base2 < R; base2 += 2 * h) {
            #pragma unroll
            for (int i = 0; i < h; ++i) {
                const float2 W  = w32t((16 * i) / h);
                const float2 tt = cmulf(W, z[base2 + i + h]);
                const float2 aa = z[base2 + i];
                z[base2 + i]     = cadd(aa, tt);
                z[base2 + i + h] = csub(aa, tt);
            }
        }
    }

    // 2) twiddle w_N^(l*r), iterated powers of wl
    {
        float2 wr = make_float2(1.0f, 0.0f);
        #pragma unroll
        for (int r = 1; r < R; ++r) {
            wr = cmulf(wr, wl);
            z[r] = cmulf(z[r], wr);
        }
    }

    // 3) cross-lane 64-point DIF FFT (output index s = lane p)
#define XSTAGE(MASK, W) { \
        _Pragma("unroll") \
        for (int j = 0; j < R; ++j) { \
            const float2 xq = shx2(z[j], MASK); \
            z[j] = (p & MASK) ? cmulf(csub(xq, z[j]), W) : cadd(z[j], xq); \
        } }
    XSTAGE(1,  W32s)
    XSTAGE(2,  W16s)
    XSTAGE(4,  W8s)
    XSTAGE(8,  W4s)
    XSTAGE(16, W2s)
    #pragma unroll
    for (int j = 0; j < R; ++j) {                  // final stage: twiddle-free
        const float2 xq = shx2(z[j], 32);
        z[j] = (p & 32) ? csub(xq, z[j]) : cadd(z[j], xq);
    }
#undef XSTAGE

    // 4) rfft unpack: lane p reg r holds Z[R*p + r]; mirror Z[N-k] at lane p^63 reg R-r
#define EMIT(RR, ZK, ZN, CW, SW) { \
        const float Er = 0.5f * ((ZK).x + (ZN).x), Ei = 0.5f * ((ZK).y - (ZN).y); \
        const float Or = 0.5f * ((ZK).y + (ZN).y), Oi = -0.5f * ((ZK).x - (ZN).x); \
        const float Xr = Er + (CW) * Or + (SW) * Oi; \
        const float Xi = Ei + (CW) * Oi - (SW) * Or; \
        const float pw = Xr * Xr + Xi * Xi; \
        const int row = R * p + ((RR) ^ (p & 7)); \
        pows[row * 8 + sub] = bf16t(pw); }

    {
        float2 c = Pp;                              // angle pi*k/N at k = R*p
        {   // r = 0: mirror lane (64-p)&63, reg 0
            const float2 Zn = shidx2(z[0], mpart);
            EMIT(0, z[0], Zn, c.x, c.y)
        }
        #pragma unroll
        for (int r = 1; r < R; ++r) {
            c = cmulf(c, ub);
            const float2 Zn = shx2(z[R - r], 63);
            EMIT(r, z[r], Zn, c.x, c.y)
        }
        if (p == 0) {                               // extra bin k = N (row N unswizzled)
            const float xr = z[0].x - z[0].y;
            pows[N * 8 + sub] = bf16t(xr * xr);
        }
    }
#undef EMIT

    __syncthreads();   // pows + res ready for mel phase

    // ---- mel: out[f][m] = sum_k pow[k][f] * mel[k][m]; rows are XOR-swizzled ----
    constexpr int NCH = 25;
    constexpr int CH  = (K + NCH - 1) / NCH;
    if (tid < NCH * 20) {
        const int g  = tid % 20;                    // mel bins 4g..4g+3
        const int cc = tid / 20;                    // k-chunk
        const int k0 = cc * CH;
        const int k1 = (k0 + CH < K) ? (k0 + CH) : K;
        float acc[FPB][4];
        #pragma unroll
        for (int f2 = 0; f2 < FPB; ++f2) {
            acc[f2][0] = 0.f; acc[f2][1] = 0.f; acc[f2][2] = 0.f; acc[f2][3] = 0.f;
        }
        for (int k = k0; k < k1; ++k) {
            const int kmel = (k & ~(R - 1)) | ((k & (R - 1)) ^ ((k >> LOGR) & 7));
            const float4 mr = *(const float4*)(mel + (size_t)kmel * NMEL + 4 * g);
            const uint4 pv = pows4[k];
#define ACC2(W32, BASE) { \
            const float p0 = __uint_as_float((W32) << 16); \
            const float p1 = __uint_as_float((W32) & 0xFFFF0000u); \
            acc[BASE][0] += p0 * mr.x; acc[BASE][1] += p0 * mr.y; \
            acc[BASE][2] += p0 * mr.z; acc[BASE][3] += p0 * mr.w; \
            acc[(BASE)+1][0] += p1 * mr.x; acc[(BASE)+1][1] += p1 * mr.y; \
            acc[(BASE)+1][2] += p1 * mr.z; acc[(BASE)+1][3] += p1 * mr.w; }
            ACC2(pv.x, 0) ACC2(pv.y, 2) ACC2(pv.z, 4) ACC2(pv.w, 6)
#undef ACC2
        }
        #pragma unroll
        for (int f2 = 0; f2 < FPB; ++f2) {
            #pragma unroll
            for (int mi = 0; mi < 4; ++mi) {
                atomicAdd(&res[f2 * NMEL + 4 * g + mi], acc[f2][mi]);
            }
        }
    }
    __syncthreads();

    const size_t outbase = (size_t)b * (size_t)n0 * NMEL * 3;
    for (int i = tid; i < FPB * NMEL; i += NT) {
        const int f2 = i / NMEL;
        const int m  = i % NMEL;
        const int tt = t0 + f2;
        if (tt < n0) {
            out[outbase + ((size_t)tt * NMEL + m) * 3 + SZI] = logf(res[i] + 1e-16f);
        }
    }
}

extern "C" void kernel_launch(void* const* d_in, const int* in_sizes, int n_in,
                              void* d_out, int out_size, void* d_ws, size_t ws_size,
                              hipStream_t stream) {
    const float* x  = (const float*)d_in[0];
    const float* w1 = (const float*)d_in[1];
    const float* m1 = (const float*)d_in[2];
    const float* w2 = (const float*)d_in[3];
    const float* m2 = (const float*)d_in[4];
    const float* w4 = (const float*)d_in[5];
    const float* m4 = (const float*)d_in[6];
    float* out = (float*)d_out;

    const int B  = 8;
    const int T  = in_sizes[0] / B;
    const int n0 = (T + 512 + 440) / 441;   // ceil((T + 1024/2) / 441)
    const int gx = (n0 + 7) / 8;

    spect_kernel<1024, 0><<<dim3(gx, B), 512, 0, stream>>>(x, w1, m1, out, T, n0);
    spect_kernel<2048, 1><<<dim3(gx, B), 512, 0, stream>>>(x, w2, m2, out, T, n0);
    spect_kernel<4096, 2><<<dim3(gx, B), 512, 0, stream>>>(x, w4, m4, out, T, n0);
}

// Round 5
// 810.112 us; speedup vs baseline: 1.2842x; 1.2842x over previous
//
#include <hip/hip_runtime.h>
#include <math.h>

#define HOP 441
#define NMEL 80

__device__ __forceinline__ float2 cmulf(float2 a, float2 b) {
    return make_float2(a.x * b.x - a.y * b.y, a.x * b.y + a.y * b.x);
}
__device__ __forceinline__ float2 cadd(float2 a, float2 b) {
    return make_float2(a.x + b.x, a.y + b.y);
}
__device__ __forceinline__ float2 csub(float2 a, float2 b) {
    return make_float2(a.x - b.x, a.y - b.y);
}
__device__ __forceinline__ float2 shx2(float2 v, int m) {
    return make_float2(__shfl_xor(v.x, m, 64), __shfl_xor(v.y, m, 64));
}
__device__ __forceinline__ float2 shidx2(float2 v, int src) {
    return make_float2(__shfl(v.x, src, 64), __shfl(v.y, src, 64));
}
__device__ __forceinline__ int brev6f(int v) {
    return ((v & 1) << 5) | ((v & 2) << 3) | ((v & 4) << 1) |
           ((v & 8) >> 1) | ((v & 16) >> 3) | ((v & 32) >> 5);
}
__device__ __forceinline__ int brevn(int v, int bits) {
    int r = 0;
    for (int i = 0; i < bits; ++i) r |= ((v >> i) & 1) << (bits - 1 - i);
    return r;
}
// w32(m) = exp(-2*pi*i*m/32), m in [0,16) — compile-time constants
__device__ __forceinline__ float2 w32t(int m) {
    constexpr float C[16] = {1.0f, 0.980785280f, 0.923879533f, 0.831469612f,
                             0.707106781f, 0.555570233f, 0.382683432f, 0.195090322f,
                             0.0f, -0.195090322f, -0.382683432f, -0.555570233f,
                             -0.707106781f, -0.831469612f, -0.923879533f, -0.980785280f};
    constexpr float S[16] = {0.0f, 0.195090322f, 0.382683432f, 0.555570233f,
                             0.707106781f, 0.831469612f, 0.923879533f, 0.980785280f,
                             1.0f, 0.980785280f, 0.923879533f, 0.831469612f,
                             0.707106781f, 0.555570233f, 0.382683432f, 0.195090322f};
    return make_float2(C[m], -S[m]);
}
__device__ __forceinline__ unsigned short bf16t(float v) {
    return (unsigned short)(__float_as_uint(v) >> 16);
}

// One wave = one frame, natural lane labeling (coalesced loads):
//  1) lane-local R-point DIT FFT over q (samples x[64q+p], reg j holds q=brev(j))
//  2) per-lane twiddle w_N^(p*r)
//  3) cross-lane 64-pt DIF FFT via shfl_xor masks 32..1; twiddle/sign folded into
//     per-lane constants (z' = (xq + sgn*z) * W'). Output at lane p is s=brev6(p).
//  4) rfft unpack: mirror bin N-k = shfl_xor(...,63) (brev commutes with xor);
//     bf16 power -> row-swizzled LDS. 8 waves = 8 frames; 1 barrier; shared mel.
template<int FLEN, int SZI>
__global__ __launch_bounds__(512, 4)
void spect_kernel(const float* __restrict__ x, const float* __restrict__ win,
                  const float* __restrict__ mel, float* __restrict__ out,
                  int T, int n0) {
    constexpr int N    = FLEN / 2;                  // complex FFT size
    constexpr int R    = N / 64;                    // regs (complex) per lane
    constexpr int LOGR = (R == 32) ? 5 : ((R == 16) ? 4 : 3);
    constexpr int K    = N + 1;                     // rfft bins
    constexpr int KP   = N + 8;
    constexpr int HALF = FLEN / 2;
    constexpr int NT   = 512;
    constexpr int FPB  = 8;                         // frames per block (= waves)
    constexpr float PI = 3.14159265358979f;

    __shared__ uint4 pows4[KP];                     // bf16 power, row-swizzled [k][frame8]
    __shared__ float res[FPB * NMEL];
    unsigned short* pows = (unsigned short*)pows4;

    const int tid = threadIdx.x;
    const int sub = tid >> 6;                       // wave = frame
    const int p   = tid & 63;                       // lane = input index l
    const int s   = brev6f(p);                      // output bin block held by this lane
    const int b   = blockIdx.y;
    const int t0  = blockIdx.x * FPB;

    for (int i = tid; i < FPB * NMEL; i += NT) res[i] = 0.0f;

    // per-lane stage constants: W' = (p&m)? w_{2m}^{p&(m-1)} : 1 ; sgn = (p&m)? -1:+1
    float2 W32s, W16s, W8s, W4s, wl, Pp, ub;
    float sg32, sg16, sg8, sg4, sg2;
    float2 W2s;
    {
        float s_, c_;
        __sincosf(-PI * (float)(p & 31) / 32.0f, &s_, &c_);
        W32s = (p & 32) ? make_float2(c_, s_) : make_float2(1.0f, 0.0f);
        sg32 = (p & 32) ? -1.0f : 1.0f;
        __sincosf(-PI * (float)(p & 15) / 16.0f, &s_, &c_);
        W16s = (p & 16) ? make_float2(c_, s_) : make_float2(1.0f, 0.0f);
        sg16 = (p & 16) ? -1.0f : 1.0f;
        __sincosf(-PI * (float)(p & 7) / 8.0f, &s_, &c_);
        W8s  = (p & 8) ? make_float2(c_, s_) : make_float2(1.0f, 0.0f);
        sg8  = (p & 8) ? -1.0f : 1.0f;
        __sincosf(-PI * (float)(p & 3) / 4.0f, &s_, &c_);
        W4s  = (p & 4) ? make_float2(c_, s_) : make_float2(1.0f, 0.0f);
        sg4  = (p & 4) ? -1.0f : 1.0f;
        __sincosf(-PI * (float)(p & 1) / 2.0f, &s_, &c_);
        W2s  = (p & 2) ? make_float2(c_, s_) : make_float2(1.0f, 0.0f);
        sg2  = (p & 2) ? -1.0f : 1.0f;
        const float sgf = (p & 1) ? -1.0f : 1.0f;   // final stage sign
        sg2  = sg2;                                  // (keep naming)
        __sincosf(-2.0f * PI * (float)p / (float)N, &s_, &c_); wl = make_float2(c_, s_);
        __sincosf(PI * (float)s / 64.0f, &s_, &c_);             Pp = make_float2(c_, s_);
        __sincosf(PI / (float)N, &s_, &c_);                     ub = make_float2(c_, s_);
        W2s = W2s; (void)sgf;
    }
    const float sg1 = (p & 1) ? -1.0f : 1.0f;
    const int mpart = brev6f((64 - s) & 63);        // r=0 mirror partner lane

    const float* xb = x + (size_t)b * (size_t)T;
    const int Tp = T + HALF;

    const int t = t0 + sub;
    const bool valid = (t < n0);
    const int start = HOP * t;
    int pad = start + FLEN - Tp; if (pad < 0) pad = 0;
    const int base = start - pad - HALF;

    float2 z[R];
    // coalesced load: reg j holds sample q = brev(j); index i = 64q + p
    #pragma unroll
    for (int j = 0; j < R; ++j) {
        const int q  = brevn(j, LOGR);
        const int i  = 64 * q + p;
        const int j0 = 2 * i;
        const float2 wv = ((const float2*)win)[i];
        const int xi0 = base + j0;
        float v0 = (valid && j0 >= pad     && xi0 >= 0)     ? xb[xi0] * wv.x     : 0.0f;
        float v1 = (valid && j0 + 1 >= pad && xi0 + 1 >= 0) ? xb[xi0 + 1] * wv.y : 0.0f;
        z[j] = make_float2(v0, v1);
    }

    // 1) lane-local R-point DIT FFT (output natural order r = reg index)
    #pragma unroll
    for (int h = 1; h < R; h <<= 1) {
        #pragma unroll
        for (int base2 = 0; base2 < R; base2 += 2 * h) {
            #pragma unroll
            for (int i = 0; i < h; ++i) {
                const float2 W  = w32t((16 * i) / h);
                const float2 tt = cmulf(W, z[base2 + i + h]);
                const float2 aa = z[base2 + i];
                z[base2 + i]     = cadd(aa, tt);
                z[base2 + i + h] = csub(aa, tt);
            }
        }
    }

    // 2) twiddle w_N^(p*r), iterated powers
    {
        float2 wr = make_float2(1.0f, 0.0f);
        #pragma unroll
        for (int r = 1; r < R; ++r) {
            wr = cmulf(wr, wl);
            z[r] = cmulf(z[r], wr);
        }
    }

    // 3) cross-lane 64-point DIF FFT, masks 32..2 twiddled, mask 1 free
#define XSTAGE(MASK, W, SG) { \
        _Pragma("unroll") \
        for (int j = 0; j < R; ++j) { \
            const float2 xq = shx2(z[j], MASK); \
            const float2 d = make_float2(fmaf(SG, z[j].x, xq.x), \
                                         fmaf(SG, z[j].y, xq.y)); \
            z[j] = cmulf(d, W); \
        } }
    XSTAGE(32, W32s, sg32)
    XSTAGE(16, W16s, sg16)
    XSTAGE(8,  W8s,  sg8)
    XSTAGE(4,  W4s,  sg4)
    XSTAGE(2,  W2s,  sg2)
    #pragma unroll
    for (int j = 0; j < R; ++j) {                   // final stage: twiddle-free
        const float2 xq = shx2(z[j], 1);
        z[j] = make_float2(fmaf(sg1, z[j].x, xq.x), fmaf(sg1, z[j].y, xq.y));
    }
#undef XSTAGE

    // 4) rfft unpack: lane p reg r holds Z[R*s + r]; mirror Z[N-k] at lane p^63 reg R-r
#define EMIT(RR, ZK, ZN, CW, SW) { \
        const float Er = 0.5f * ((ZK).x + (ZN).x), Ei = 0.5f * ((ZK).y - (ZN).y); \
        const float Or = 0.5f * ((ZK).y + (ZN).y), Oi = -0.5f * ((ZK).x - (ZN).x); \
        const float Xr = Er + (CW) * Or + (SW) * Oi; \
        const float Xi = Ei + (CW) * Oi - (SW) * Or; \
        const float pw = Xr * Xr + Xi * Xi; \
        const int row = R * s + ((RR) ^ (s & 7)); \
        pows[row * 8 + sub] = bf16t(pw); }

    {
        float2 c = Pp;                              // angle pi*k/N at k = R*s
        {   // r = 0: mirror at lane brev6((64-s)&63), reg 0
            const float2 Zn = shidx2(z[0], mpart);
            EMIT(0, z[0], Zn, c.x, c.y)
        }
        #pragma unroll
        for (int r = 1; r < R; ++r) {
            c = cmulf(c, ub);
            const float2 Zn = shx2(z[R - r], 63);
            EMIT(r, z[r], Zn, c.x, c.y)
        }
        if (p == 0) {                               // bin k = N (s=0 lane holds Z[0])
            const float xr = z[0].x - z[0].y;
            pows[N * 8 + sub] = bf16t(xr * xr);
        }
    }
#undef EMIT

    __syncthreads();   // pows + res ready for mel phase

    // ---- mel: out[f][m] = sum_k pow[k][f] * mel[k][m]; rows XOR-swizzled ----
    constexpr int NCH = 25;
    constexpr int CH  = (K + NCH - 1) / NCH;
    if (tid < NCH * 20) {
        const int g  = tid % 20;                    // mel bins 4g..4g+3
        const int cc = tid / 20;                    // k-chunk
        const int k0 = cc * CH;
        const int k1 = (k0 + CH < K) ? (k0 + CH) : K;
        float acc[FPB][4];
        #pragma unroll
        for (int f2 = 0; f2 < FPB; ++f2) {
            acc[f2][0] = 0.f; acc[f2][1] = 0.f; acc[f2][2] = 0.f; acc[f2][3] = 0.f;
        }
        for (int k = k0; k < k1; ++k) {
            const int kmel = (k & ~(R - 1)) | ((k & (R - 1)) ^ ((k >> LOGR) & 7));
            const float4 mr = *(const float4*)(mel + (size_t)kmel * NMEL + 4 * g);
            const uint4 pv = pows4[k];
#define ACC2(W32, BASE) { \
            const float p0 = __uint_as_float((W32) << 16); \
            const float p1 = __uint_as_float((W32) & 0xFFFF0000u); \
            acc[BASE][0] += p0 * mr.x; acc[BASE][1] += p0 * mr.y; \
            acc[BASE][2] += p0 * mr.z; acc[BASE][3] += p0 * mr.w; \
            acc[(BASE)+1][0] += p1 * mr.x; acc[(BASE)+1][1] += p1 * mr.y; \
            acc[(BASE)+1][2] += p1 * mr.z; acc[(BASE)+1][3] += p1 * mr.w; }
            ACC2(pv.x, 0) ACC2(pv.y, 2) ACC2(pv.z, 4) ACC2(pv.w, 6)
#undef ACC2
        }
        #pragma unroll
        for (int f2 = 0; f2 < FPB; ++f2) {
            #pragma unroll
            for (int mi = 0; mi < 4; ++mi) {
                atomicAdd(&res[f2 * NMEL + 4 * g + mi], acc[f2][mi]);
            }
        }
    }
    __syncthreads();

    const size_t outbase = (size_t)b * (size_t)n0 * NMEL * 3;
    for (int i = tid; i < FPB * NMEL; i += NT) {
        const int f2 = i / NMEL;
        const int m  = i % NMEL;
        const int tt = t0 + f2;
        if (tt < n0) {
            out[outbase + ((size_t)tt * NMEL + m) * 3 + SZI] = logf(res[i] + 1e-16f);
        }
    }
}

extern "C" void kernel_launch(void* const* d_in, const int* in_sizes, int n_in,
                              void* d_out, int out_size, void* d_ws, size_t ws_size,
                              hipStream_t stream) {
    const float* x  = (const float*)d_in[0];
    const float* w1 = (const float*)d_in[1];
    const float* m1 = (const float*)d_in[2];
    const float* w2 = (const float*)d_in[3];
    const float* m2 = (const float*)d_in[4];
    const float* w4 = (const float*)d_in[5];
    const float* m4 = (const float*)d_in[6];
    float* out = (float*)d_out;

    const int B  = 8;
    const int T  = in_sizes[0] / B;
    const int n0 = (T + 512 + 440) / 441;   // ceil((T + 1024/2) / 441)
    const int gx = (n0 + 7) / 8;

    spect_kernel<1024, 0><<<dim3(gx, B), 512, 0, stream>>>(x, w1, m1, out, T, n0);
    spect_kernel<2048, 1><<<dim3(gx, B), 512, 0, stream>>>(x, w2, m2, out, T, n0);
    spect_kernel<4096, 2><<<dim3(gx, B), 512, 0, stream>>>(x, w4, m4, out, T, n0);
}